// Round 15
// baseline (57.105 us; speedup 1.0000x reference)
//
#include <hip/hip_runtime.h>
#include <stdint.h>

#define UNITS  512
#define IN_DIM 1024
#define KCONN  32
#define BATCH  16384

#define BM 64
#define BN 256
#define BK 64
#define NT 512            // 8 waves
#define KS (IN_DIM / BK)  // 16 K-steps

typedef _Float16 f16x8 __attribute__((ext_vector_type(8)));
typedef __fp16   hf16x2 __attribute__((ext_vector_type(2)));
typedef float    f32x4 __attribute__((ext_vector_type(4)));

// ---------------- Kernel 1: top-32 per unit -> B in MFMA-fragment order ----------------
// DPP top-32 selection (r5-r14 verified). Output wsB: B fragments packed so a
// GEMM wave's 16x16x32 B-operand load is ONE coalesced 1KB global_load_dwordx4:
//   frag (ks, nh, wv, nf, kh) occupies 1024B at
//     off = ((((ks*2 + nh)*8 + wv)*2 + nf)*2 + kh) * 1024
//   lane l's 16B at off + l*16 = W'[u = nh*256+wv*32+nf*16+(l&15),
//                                  k = ks*64+kh*32+(l>>4)*8 .. +8]   (f16)
// B never touches LDS in the GEMM (the r14 fix: LDS pipe was saturated at
// 17 instrs/wave-iter; B's 8 LDS ops -> 0, A keeps 9).

template <int CTRL, int RM>
__device__ __forceinline__ float dppmax(float m) {
    int t = __builtin_amdgcn_update_dpp(0xFF800000, __float_as_int(m),
                                        CTRL, RM, 0xf, false);
    return fmaxf(m, __int_as_float(t));
}

__global__ __launch_bounds__(64) void topk_pack(const float* __restrict__ D,
                                                const float* __restrict__ GN,
                                                const float* __restrict__ W,
                                                char* __restrict__ wsB) {
    const int u = blockIdx.x;
    const int l = threadIdx.x;

    float cand[16];
#pragma unroll
    for (int j = 0; j < 16; ++j) {
        int i = l + 64 * j;                          // coalesced
        cand[j] = D[u * IN_DIM + i] + GN[u * IN_DIM + i];
    }

    int mykeep = -1;

    for (int t = 0; t < KCONN; ++t) {
        float bv = cand[0];
        int bs = 0;
#pragma unroll
        for (int j = 1; j < 16; ++j) {
            bool gt = cand[j] > bv;
            bv = gt ? cand[j] : bv;
            bs = gt ? j : bs;
        }
        float m = bv;
        m = dppmax<0x111, 0xf>(m);
        m = dppmax<0x112, 0xf>(m);
        m = dppmax<0x114, 0xf>(m);
        m = dppmax<0x118, 0xf>(m);
        m = dppmax<0x142, 0xa>(m);   // row_bcast15 -> rows 1,3
        m = dppmax<0x143, 0xc>(m);   // row_bcast31 -> rows 2,3
        float gmax = __int_as_float(__builtin_amdgcn_readlane(__float_as_int(m), 63));

        unsigned long long mask = __ballot(bv == gmax);
        int owner = __ffsll((long long)mask) - 1;
        int slot = __builtin_amdgcn_readlane(bs, owner);
        int idx = slot * 64 + owner;

        if (l == t) mykeep = idx;
        bool own = (l == owner);
#pragma unroll
        for (int j = 0; j < 16; ++j)
            cand[j] = (own && j == slot) ? -__builtin_huge_valf() : cand[j];
    }

    __shared__ uint32_t rowbuf[IN_DIM / 2];          // dense f16 row, 2 KB
#pragma unroll
    for (int j = 0; j < 8; ++j) rowbuf[l + 64 * j] = 0;
    __syncthreads();
    if (l < KCONN) {
        union { _Float16 h; uint16_t b; } cv;
        cv.h = (_Float16)W[u * IN_DIM + mykeep];
        ((uint16_t*)rowbuf)[mykeep] = cv.b;
    }
    __syncthreads();

    const int nh = u >> 8, wv = (u >> 5) & 7, nf = (u >> 4) & 1, ur = u & 15;
#pragma unroll
    for (int j = 0; j < 2; ++j) {
        const int g = l + 64 * j;                    // k-octet 0..127 (8 f16)
        const int ks = g >> 3, kh = (g >> 2) & 1, kg = g & 3;
        const size_t off = ((((size_t)ks * 2 + nh) * 8 + wv) * 2 + nf) * 2 + kh;
        *(uint4*)(wsB + off * 1024 + (kg * 16 + ur) * 16) =
            ((const uint4*)rowbuf)[g];
    }
}

// ---------------- Kernel 2: f16 MFMA GEMM, B-in-registers ----------------
// y = x(f32->f16) @ W'^T + bias.  BM=64 x BN=256, BK=64, 8 waves, grid 512
// (bid>>1 = m-tile, bid&1 = n-half), LDS 16 KB (A dbuf only).
// Per iter: BLOAD(next B frags -> regs, 4x coalesced 1KB from L2)
//           COMPUTE (8x ds_read_b128 A + 16 MFMA, B from regs)
//           CVTWRITE (x f32->pkrtz-> 1 ds_write_b128 into As[nxt])
//           LOADV (x for ks+3, 2-deep reg prefetch)
//           s_waitcnt lgkmcnt(0); s_barrier   <- NO vmcnt: nothing in LDS
//           comes from VMEM; B/x prefetches fly across the barrier.
// A swizzle (r10-verified): phys = row*128 + (kb ^ ((row&7)<<4)) -> 2-way max.

#define FENCE() asm volatile("" ::: "memory")

__device__ __forceinline__ uint32_t pkrtz(float a, float b) {
    union { hf16x2 h; uint32_t u; } cv;
    cv.h = __builtin_amdgcn_cvt_pkrtz(a, b);
    return cv.u;
}

__global__ __launch_bounds__(NT, 4) void gemm_kernel(const float* __restrict__ x,
                                                     const float* __restrict__ bias,
                                                     const char* __restrict__ wsB,
                                                     float* __restrict__ y) {
    __shared__ char As[2][BM * 128];                // 2 x 8 KB

    const int tid = threadIdx.x;
    const int w = tid >> 6;                         // wave 0..7
    const int l = tid & 63;
    const int mb = ((int)blockIdx.x >> 1) * BM;
    const int nh = (int)blockIdx.x & 1;
    const int nb = nh * BN;

    // A staging: thread -> row tid>>3, k-octet tid&7 (8 f32 -> 16B f16)
    const int arow = tid >> 3;
    const int akq = tid & 7;
    const float* xp0 = x + (size_t)(mb + arow) * IN_DIM + akq * 8;
    const uint32_t aoff = (uint32_t)(arow * 128) +
                          (((uint32_t)akq ^ (uint32_t)(arow & 7)) << 4);

    // B fragment base for this (nh, w): + l*16; frag (ks,nf,kh) at +ks*64K+nf*2K+kh*1K
    const char* wsBb = wsB + (size_t)(nh * 32 + w * 4) * 1024 + (size_t)l * 16;

    float4 va1, va2, vb1, vb2;
    f16x8 b0[4], b1[4];                             // [nf*2+kh], two named sets
    f32x4 acc[4][2] = {};

#define LOADV(r1, r2, kss)                                                       \
    {                                                                            \
        const float4* p = (const float4*)(xp0 + (size_t)(kss) * BK);             \
        r1 = p[0]; r2 = p[1];                                                    \
    }

#define CVTWRITE(buf)                                                            \
    *(uint4*)(As[buf] + aoff) =                                                  \
        make_uint4(pkrtz(va1.x, va1.y), pkrtz(va1.z, va1.w),                     \
                   pkrtz(va2.x, va2.y), pkrtz(va2.z, va2.w));

#define BLOAD(br, kss)                                                           \
    {                                                                            \
        const char* bb = wsBb + (size_t)(kss) * 65536;                           \
        br[0] = *(const f16x8*)(bb);                                             \
        br[1] = *(const f16x8*)(bb + 1024);                                      \
        br[2] = *(const f16x8*)(bb + 2048);                                      \
        br[3] = *(const f16x8*)(bb + 3072);                                      \
    }

#define COMPUTE(buf, br)                                                         \
    {                                                                            \
        _Pragma("unroll")                                                        \
        for (int kh = 0; kh < 2; ++kh) {                                         \
            f16x8 af[4];                                                         \
            const uint32_t kb = (uint32_t)(kh * 64 + ((l >> 4) << 4));           \
            _Pragma("unroll")                                                    \
            for (int mf = 0; mf < 4; ++mf) {                                     \
                const int row = mf * 16 + (l & 15);                              \
                af[mf] = *(const f16x8*)(As[buf] + row * 128 +                   \
                                         (kb ^ ((uint32_t)(row & 7) << 4)));     \
            }                                                                    \
            _Pragma("unroll")                                                    \
            for (int mf = 0; mf < 4; ++mf)                                       \
                _Pragma("unroll")                                                \
                for (int nf = 0; nf < 2; ++nf)                                   \
                    acc[mf][nf] = __builtin_amdgcn_mfma_f32_16x16x32_f16(        \
                        af[mf], br[nf * 2 + kh], acc[mf][nf], 0, 0, 0);          \
        }                                                                        \
    }

#define ITER(ks, bc, bn)                                                         \
    {                                                                            \
        BLOAD(bn, ((ks) + 1 < KS) ? (ks) + 1 : KS - 1);                          \
        FENCE();                                                                 \
        COMPUTE((ks) & 1, bc);                                                   \
        CVTWRITE(((ks) + 1) & 1);                                                \
        {                                                                        \
            const int kld = ((ks) + 3 < KS) ? (ks) + 3 : KS - 1;                 \
            LOADV(va1, va2, kld);                                                \
        }                                                                        \
        { float4 t1 = va1, t2 = va2; va1 = vb1; va2 = vb2; vb1 = t1; vb2 = t2; } \
        asm volatile("s_waitcnt lgkmcnt(0)" ::: "memory");                       \
        __builtin_amdgcn_s_barrier();                                            \
    }

    // ---- prologue: As[0] <- x(0); B(0) -> b0; va=x(1), vb=x(2) ----
    LOADV(va1, va2, 0);
    BLOAD(b0, 0);
    FENCE();
    CVTWRITE(0);                                    // compiler waits va only
    LOADV(va1, va2, 1);
    LOADV(vb1, vb2, 2);
    asm volatile("s_waitcnt lgkmcnt(0)" ::: "memory");
    __builtin_amdgcn_s_barrier();

    // ---- main loop: 8 pairs, all 16 COMPUTEs inside ----
    for (int kp = 0; kp < KS / 2; ++kp) {
        ITER(2 * kp, b0, b1);
        ITER(2 * kp + 1, b1, b0);
    }

    // ---- epilogue: y = acc + bias ----
#pragma unroll
    for (int nf = 0; nf < 2; ++nf) {
        const int n = nb + w * 32 + nf * 16 + (l & 15);
        const float bv = bias[n];
#pragma unroll
        for (int mf = 0; mf < 4; ++mf) {
            const int m0 = mb + mf * 16 + ((l >> 4) << 2);
#pragma unroll
            for (int r = 0; r < 4; ++r)
                y[(size_t)(m0 + r) * UNITS + n] = acc[mf][nf][r] + bv;
        }
    }
#undef LOADV
#undef CVTWRITE
#undef BLOAD
#undef COMPUTE
#undef ITER
}

extern "C" void kernel_launch(void* const* d_in, const int* in_sizes, int n_in,
                              void* d_out, int out_size, void* d_ws, size_t ws_size,
                              hipStream_t stream) {
    const float* x  = (const float*)d_in[0];   // [16384,1024]
    const float* W  = (const float*)d_in[1];   // [512,1024]
    const float* bv = (const float*)d_in[2];   // [512]
    const float* D  = (const float*)d_in[3];   // [512,1024]
    const float* GN = (const float*)d_in[4];   // [1,512,1024]
    float* y = (float*)d_out;                  // [16384,512]

    char* wsB = (char*)d_ws;                   // fragment-packed B, 2 MB

    topk_pack<<<UNITS, 64, 0, stream>>>(D, GN, W, wsB);
    gemm_kernel<<<(BATCH / BM) * (UNITS / BN), NT, 0, stream>>>(x, bv, wsB, y);
}

// Round 16
// 54.892 us; speedup vs baseline: 1.0403x; 1.0403x over previous
//
#include <hip/hip_runtime.h>
#include <stdint.h>

#define UNITS  512
#define IN_DIM 1024
#define KCONN  32
#define BATCH  16384

#define BM 64
#define BN 256
#define BK 64
#define NT 512            // 8 waves
#define KS (IN_DIM / BK)  // 16 K-steps

typedef _Float16 f16x8 __attribute__((ext_vector_type(8)));
typedef __fp16   hf16x2 __attribute__((ext_vector_type(2)));
typedef float    f32x4 __attribute__((ext_vector_type(4)));

// ---------------- Kernel 1: top-32 per unit -> B in MFMA-fragment order ----------------
// DPP top-32 selection (r5-r15 verified). Output wsB: B fragments packed so a
// GEMM wave's 16x16x32 B-operand load is ONE coalesced 1KB global_load_dwordx4:
//   frag (ks, nh, wv, nf, kh) occupies 1024B at
//     off = ((((ks*2 + nh)*8 + wv)*2 + nf)*2 + kh) * 1024
//   lane l's 16B at off + l*16 = W'[u = nh*256+wv*32+nf*16+(l&15),
//                                  k = ks*64+kh*32+(l>>4)*8 .. +8]   (f16)
// B never touches LDS in the GEMM (r14's LDS pipe was the pacer at 17
// instrs/wave-iter; B's 8 LDS ops -> 0, A keeps 9).

template <int CTRL, int RM>
__device__ __forceinline__ float dppmax(float m) {
    int t = __builtin_amdgcn_update_dpp(0xFF800000, __float_as_int(m),
                                        CTRL, RM, 0xf, false);
    return fmaxf(m, __int_as_float(t));
}

__global__ __launch_bounds__(64) void topk_pack(const float* __restrict__ D,
                                                const float* __restrict__ GN,
                                                const float* __restrict__ W,
                                                char* __restrict__ wsB) {
    const int u = blockIdx.x;
    const int l = threadIdx.x;

    float cand[16];
#pragma unroll
    for (int j = 0; j < 16; ++j) {
        int i = l + 64 * j;                          // coalesced
        cand[j] = D[u * IN_DIM + i] + GN[u * IN_DIM + i];
    }

    int mykeep = -1;

    for (int t = 0; t < KCONN; ++t) {
        float bv = cand[0];
        int bs = 0;
#pragma unroll
        for (int j = 1; j < 16; ++j) {
            bool gt = cand[j] > bv;
            bv = gt ? cand[j] : bv;
            bs = gt ? j : bs;
        }
        float m = bv;
        m = dppmax<0x111, 0xf>(m);
        m = dppmax<0x112, 0xf>(m);
        m = dppmax<0x114, 0xf>(m);
        m = dppmax<0x118, 0xf>(m);
        m = dppmax<0x142, 0xa>(m);   // row_bcast15 -> rows 1,3
        m = dppmax<0x143, 0xc>(m);   // row_bcast31 -> rows 2,3
        float gmax = __int_as_float(__builtin_amdgcn_readlane(__float_as_int(m), 63));

        unsigned long long mask = __ballot(bv == gmax);
        int owner = __ffsll((long long)mask) - 1;
        int slot = __builtin_amdgcn_readlane(bs, owner);
        int idx = slot * 64 + owner;

        if (l == t) mykeep = idx;
        bool own = (l == owner);
#pragma unroll
        for (int j = 0; j < 16; ++j)
            cand[j] = (own && j == slot) ? -__builtin_huge_valf() : cand[j];
    }

    __shared__ uint32_t rowbuf[IN_DIM / 2];          // dense f16 row, 2 KB
#pragma unroll
    for (int j = 0; j < 8; ++j) rowbuf[l + 64 * j] = 0;
    __syncthreads();
    if (l < KCONN) {
        union { _Float16 h; uint16_t b; } cv;
        cv.h = (_Float16)W[u * IN_DIM + mykeep];
        ((uint16_t*)rowbuf)[mykeep] = cv.b;
    }
    __syncthreads();

    const int nh = u >> 8, wv = (u >> 5) & 7, nf = (u >> 4) & 1, ur = u & 15;
#pragma unroll
    for (int j = 0; j < 2; ++j) {
        const int g = l + 64 * j;                    // k-octet 0..127 (8 f16)
        const int ks = g >> 3, kh = (g >> 2) & 1, kg = g & 3;
        const size_t off = ((((size_t)ks * 2 + nh) * 8 + wv) * 2 + nf) * 2 + kh;
        *(uint4*)(wsB + off * 1024 + (kg * 16 + ur) * 16) =
            ((const uint4*)rowbuf)[g];
    }
}

// ---------------- Kernel 2: f16 MFMA GEMM, B-in-registers ----------------
// y = x(f32->f16) @ W'^T + bias.  BM=64 x BN=256, BK=64, 8 waves, grid 512
// (bid>>1 = m-tile, bid&1 = n-half), LDS 16 KB (A dbuf only).
// r15 post-mortem: launch_bounds(512,4) made the allocator target 64 VGPRs
// and SPILL the B double-buffer (WRITE_SIZE +24MB of scratch). Fix:
// launch_bounds(512,2) -> cap 256, live set ~110 fits, no spill; occupancy
// still 2 blocks/CU (LDS 16KB, VGPR ~110 -> 4+ waves/SIMD).
// Per iter: BLOAD(next B frags -> regs, 4x coalesced 1KB from L2)
//           COMPUTE (8x ds_read_b128 A + 16 MFMA, B from regs)
//           CVTWRITE (x f32->pkrtz -> 1 ds_write_b128 into As[nxt])
//           LOADV (x for ks+3, 2-deep reg prefetch)
//           s_waitcnt lgkmcnt(0); s_barrier   <- NO vmcnt: nothing in LDS
//           comes from VMEM; B/x prefetches fly across the barrier.
// A swizzle (r10-verified): phys = row*128 + (kb ^ ((row&7)<<4)) -> 2-way max.

#define FENCE() asm volatile("" ::: "memory")

__device__ __forceinline__ uint32_t pkrtz(float a, float b) {
    union { hf16x2 h; uint32_t u; } cv;
    cv.h = __builtin_amdgcn_cvt_pkrtz(a, b);
    return cv.u;
}

__global__ __launch_bounds__(NT, 2) void gemm_kernel(const float* __restrict__ x,
                                                     const float* __restrict__ bias,
                                                     const char* __restrict__ wsB,
                                                     float* __restrict__ y) {
    __shared__ char As[2][BM * 128];                // 2 x 8 KB

    const int tid = threadIdx.x;
    const int w = tid >> 6;                         // wave 0..7
    const int l = tid & 63;
    const int mb = ((int)blockIdx.x >> 1) * BM;
    const int nh = (int)blockIdx.x & 1;
    const int nb = nh * BN;

    // A staging: thread -> row tid>>3, k-octet tid&7 (8 f32 -> 16B f16)
    const int arow = tid >> 3;
    const int akq = tid & 7;
    const float* xp0 = x + (size_t)(mb + arow) * IN_DIM + akq * 8;
    const uint32_t aoff = (uint32_t)(arow * 128) +
                          (((uint32_t)akq ^ (uint32_t)(arow & 7)) << 4);

    // B fragment base for this (nh, w): + l*16; frag (ks,nf,kh) at +ks*64K+nf*2K+kh*1K
    const char* wsBb = wsB + (size_t)(nh * 32 + w * 4) * 1024 + (size_t)l * 16;

    float4 va1, va2, vb1, vb2;
    f16x8 b0[4], b1[4];                             // [nf*2+kh], two named sets
    f32x4 acc[4][2] = {};

#define LOADV(r1, r2, kss)                                                       \
    {                                                                            \
        const float4* p = (const float4*)(xp0 + (size_t)(kss) * BK);             \
        r1 = p[0]; r2 = p[1];                                                    \
    }

#define CVTWRITE(buf)                                                            \
    *(uint4*)(As[buf] + aoff) =                                                  \
        make_uint4(pkrtz(va1.x, va1.y), pkrtz(va1.z, va1.w),                     \
                   pkrtz(va2.x, va2.y), pkrtz(va2.z, va2.w));

#define BLOAD(br, kss)                                                           \
    {                                                                            \
        const char* bb = wsBb + (size_t)(kss) * 65536;                           \
        br[0] = *(const f16x8*)(bb);                                             \
        br[1] = *(const f16x8*)(bb + 1024);                                      \
        br[2] = *(const f16x8*)(bb + 2048);                                      \
        br[3] = *(const f16x8*)(bb + 3072);                                      \
    }

#define COMPUTE(buf, br)                                                         \
    {                                                                            \
        _Pragma("unroll")                                                        \
        for (int kh = 0; kh < 2; ++kh) {                                         \
            f16x8 af[4];                                                         \
            const uint32_t kb = (uint32_t)(kh * 64 + ((l >> 4) << 4));           \
            _Pragma("unroll")                                                    \
            for (int mf = 0; mf < 4; ++mf) {                                     \
                const int row = mf * 16 + (l & 15);                              \
                af[mf] = *(const f16x8*)(As[buf] + row * 128 +                   \
                                         (kb ^ ((uint32_t)(row & 7) << 4)));     \
            }                                                                    \
            _Pragma("unroll")                                                    \
            for (int mf = 0; mf < 4; ++mf)                                       \
                _Pragma("unroll")                                                \
                for (int nf = 0; nf < 2; ++nf)                                   \
                    acc[mf][nf] = __builtin_amdgcn_mfma_f32_16x16x32_f16(        \
                        af[mf], br[nf * 2 + kh], acc[mf][nf], 0, 0, 0);          \
        }                                                                        \
    }

#define ITER(ks, bc, bn)                                                         \
    {                                                                            \
        BLOAD(bn, ((ks) + 1 < KS) ? (ks) + 1 : KS - 1);                          \
        FENCE();                                                                 \
        COMPUTE((ks) & 1, bc);                                                   \
        CVTWRITE(((ks) + 1) & 1);                                                \
        {                                                                        \
            const int kld = ((ks) + 3 < KS) ? (ks) + 3 : KS - 1;                 \
            LOADV(va1, va2, kld);                                                \
        }                                                                        \
        { float4 t1 = va1, t2 = va2; va1 = vb1; va2 = vb2; vb1 = t1; vb2 = t2; } \
        asm volatile("s_waitcnt lgkmcnt(0)" ::: "memory");                       \
        __builtin_amdgcn_s_barrier();                                            \
    }

    // ---- prologue: As[0] <- x(0); B(0) -> b0; va=x(1), vb=x(2) ----
    LOADV(va1, va2, 0);
    BLOAD(b0, 0);
    FENCE();
    CVTWRITE(0);                                    // compiler waits va only
    LOADV(va1, va2, 1);
    LOADV(vb1, vb2, 2);
    asm volatile("s_waitcnt lgkmcnt(0)" ::: "memory");
    __builtin_amdgcn_s_barrier();

    // ---- main loop: 8 pairs, all 16 COMPUTEs inside ----
    for (int kp = 0; kp < KS / 2; ++kp) {
        ITER(2 * kp, b0, b1);
        ITER(2 * kp + 1, b1, b0);
    }

    // ---- epilogue: y = acc + bias ----
#pragma unroll
    for (int nf = 0; nf < 2; ++nf) {
        const int n = nb + w * 32 + nf * 16 + (l & 15);
        const float bv = bias[n];
#pragma unroll
        for (int mf = 0; mf < 4; ++mf) {
            const int m0 = mb + mf * 16 + ((l >> 4) << 2);
#pragma unroll
            for (int r = 0; r < 4; ++r)
                y[(size_t)(m0 + r) * UNITS + n] = acc[mf][nf][r] + bv;
        }
    }
#undef LOADV
#undef CVTWRITE
#undef BLOAD
#undef COMPUTE
#undef ITER
}

extern "C" void kernel_launch(void* const* d_in, const int* in_sizes, int n_in,
                              void* d_out, int out_size, void* d_ws, size_t ws_size,
                              hipStream_t stream) {
    const float* x  = (const float*)d_in[0];   // [16384,1024]
    const float* W  = (const float*)d_in[1];   // [512,1024]
    const float* bv = (const float*)d_in[2];   // [512]
    const float* D  = (const float*)d_in[3];   // [512,1024]
    const float* GN = (const float*)d_in[4];   // [1,512,1024]
    float* y = (float*)d_out;                  // [16384,512]

    char* wsB = (char*)d_ws;                   // fragment-packed B, 2 MB

    topk_pack<<<UNITS, 64, 0, stream>>>(D, GN, W, wsB);
    gemm_kernel<<<(BATCH / BM) * (UNITS / BN), NT, 0, stream>>>(x, bv, wsB, y);
}